// Round 7
// baseline (237.717 us; speedup 1.0000x reference)
//
#include <hip/hip_runtime.h>
#include <hip/hip_bf16.h>
#include <stdint.h>

// Problem constants
#define BB 8
#define SS 2048
#define NEXP 16
#define DIN 1024
#define DOUT 1024

typedef short bf16x8 __attribute__((ext_vector_type(8)));
typedef float floatx4 __attribute__((ext_vector_type(4)));

// fp32 -> bf16 round-to-nearest-even (bit trick; inputs are normal floats)
__device__ __forceinline__ unsigned short f2bf(float f) {
    union { float f; unsigned int u; } v; v.f = f;
    unsigned int u = v.u;
    unsigned int r = u + 0x7FFFu + ((u >> 16) & 1u);
    return (unsigned short)(r >> 16);
}

// 2x fp32 -> packed bf16x2 (hardware v_cvt_pk_bf16_f32, RNE)
__device__ __forceinline__ unsigned pk2(float a, float b) {
    __hip_bfloat162 h = __float22bfloat162_rn(float2{a, b});
    union { __hip_bfloat162 h; unsigned u; } cv; cv.h = h;
    return cv.u;
}

// async global->LDS, 16B per lane. LDS dest = wave-uniform base + lane*16.
__device__ __forceinline__ void gload16(const void* g, void* l) {
    __builtin_amdgcn_global_load_lds(
        (const __attribute__((address_space(1))) void*)g,
        (__attribute__((address_space(3))) void*)l,
        16, 0, 0);
}

// ---------------------------------------------------------------------------
// R10: xconv kernel DELETED. gemm stages A as RAW FP32 via async gload_lds
// (the proven fire-and-forget path — R6's failure was the synchronous
// reg-staging, not the convert) and converts fp32->bf16 on the LDS-read side
// with v_cvt_pk_bf16_f32. Removes the 96 MB xconv pass (~40 us, pinned at
// ~2.3 TB/s across 5 configurations — that pattern's ceiling, a bankable
// negative result).
// Pipeline: prep (wmix+bias, ~15 us) -> gemm (fp32-A, bf16-B).
// ---------------------------------------------------------------------------

// Kernel 1: weight mix + bias mix (proven ~15 us)
__global__ __launch_bounds__(256) void prep_kernel(
    const float* __restrict__ p, const float* __restrict__ w,
    const float* __restrict__ bias,
    unsigned short* __restrict__ mw, float* __restrict__ mb)
{
    const int tid = threadIdx.x;
    const int blk = blockIdx.x;

    if (blk < 2048) {                       // ---- weight mix ----
        __shared__ float sp[BB * NEXP];
        if (tid < BB * NEXP) sp[tid] = p[tid];
        __syncthreads();
        const long t  = (long)blk * 256 + tid;      // 0..524287
        const long j2 = t * 2;                      // column pair
        float acc[BB][2];
        #pragma unroll
        for (int b = 0; b < BB; ++b) { acc[b][0] = 0.f; acc[b][1] = 0.f; }
        #pragma unroll
        for (int n = 0; n < NEXP; ++n) {
            float2 wv = *(const float2*)(w + (long)n * DOUT * DIN + j2);
            #pragma unroll
            for (int b = 0; b < BB; ++b) {
                float pb = sp[b * NEXP + n];
                acc[b][0] += pb * wv.x; acc[b][1] += pb * wv.y;
            }
        }
        #pragma unroll
        for (int b = 0; b < BB; ++b) {
            unsigned o = (unsigned)f2bf(acc[b][0]) | ((unsigned)f2bf(acc[b][1]) << 16);
            *(unsigned*)(mw + (long)b * DOUT * DIN + j2) = o;
        }
    } else {                                // ---- bias mix (tiny) ----
        const long t = (long)(blk - 2048) * 256 + tid;    // 0..8191
        const int b = (int)(t >> 10), i = (int)(t & 1023);
        float s = 0.f;
        #pragma unroll
        for (int n = 0; n < NEXP; ++n) s += p[b * NEXP + n] * bias[n * DOUT + i];
        mb[t] = s;
    }
}

// ---------------------------------------------------------------------------
// Kernel 2: batched GEMM  out[b] = cvt_bf16(x[b]) (S x K) * mixed_w[b]^T + mb[b]
// Skeleton = R9's proven 2-barrier gload_lds loop. Deltas only:
//   - sA is FP32 [128][64] (32 KB): 2 gload16 per chunk (rows 0-3, rows 4-7).
//     fp32 row = 16 x 16B-groups; swizzle: LDS group g at row r holds global
//     col-group g ^ (r&7) (XOR low 3 of 4 group bits; bank-cluster = g mod 8,
//     same structure as the bf16 layout that measured 0 conflicts).
//   - A fragment read: 2x ds_read_b128 (float4) at groups g0=(kh*8+q*2)^rsw,
//     g1=g0^1, then 4x v_cvt_pk_bf16_f32 -> bf16x8 MFMA operand.
//     (paper check: row=5,q=1,kh=0 -> g0=7,g1=6 hold global cols 8..15 ✓)
//   - B path byte-identical to R9.
// LDS 48 KB -> 3 blocks/CU. A per-iter offset 256*t B <= 3840, folds to imm.
// ---------------------------------------------------------------------------
__global__ __launch_bounds__(256) void gemm_kernel(
    const float* __restrict__ x,             // [B][S][DIN] fp32
    const unsigned short* __restrict__ mw,   // [B][DOUT][DIN] bf16
    const float* __restrict__ mb,            // [B][DOUT] fp32
    float* __restrict__ out)                 // [B][S][DOUT] fp32
{
    __shared__ __align__(16) float          sAf[128 * 64];  // 32 KB fp32
    __shared__ __align__(16) unsigned short sB [128 * 64];  // 16 KB bf16

    const int tid  = threadIdx.x;
    const int wave = tid >> 6;
    const int lane = tid & 63;
    const int b    = blockIdx.x;          // batch -> XCD (id % 8 == b)
    const int tileN = blockIdx.y * 128;   // over DOUT
    const int tileM = blockIdx.z * 128;   // over S

    const float*          Ag = x  + (long)b * SS * DIN;
    const unsigned short* Bg = mw + (long)b * DOUT * DIN;

    const int q     = lane >> 4;     // quad 0..3
    const int r16   = lane & 15;
    const int mBase = 64 * (wave >> 1);
    const int nBase = 64 * (wave & 1);

    // ---- A staging (fp32): per chunk 8 rows x 64 fp32 = 2 KB = 2 gload16 ----
    const int g16 = lane & 15;       // 16B-group within a row (16 groups)
    const int r4  = lane >> 4;       // row within half-chunk (0..3)
    const int sc0 = ((g16 ^ r4)       ) * 4;   // src fp32 col, rows 0..3 (r&7 = r4)
    const int sc1 = ((g16 ^ (4 + r4)) ) * 4;   // src fp32 col, rows 4..7 (r&7 = 4+r4)

    // ---- B staging (bf16): per chunk 8 rows x 64 bf16 = 1 KB = 1 gload16 ----
    const int sRow   = lane >> 3;                    // 0..7 row within chunk
    const int sColSw = (((lane & 7) ^ sRow) * 8);    // XOR-swizzled source column

    const float* aSrc0[4]; const float* aSrc1[4]; const unsigned short* bSrc[4];
    float* aDst0[4]; float* aDst1[4]; unsigned short* bDst[4];
    #pragma unroll
    for (int c = 0; c < 4; ++c) {
        const int chunk = wave * 4 + c;              // 0..15
        aSrc0[c] = Ag + (long)(tileM + chunk * 8 +     r4) * DIN + sc0;
        aSrc1[c] = Ag + (long)(tileM + chunk * 8 + 4 + r4) * DIN + sc1;
        bSrc[c]  = Bg + (long)(tileN + chunk * 8 + sRow) * DIN + sColSw;
        aDst0[c] = &sAf[chunk * 512];        // rows 0..3 of chunk (linear lane*16)
        aDst1[c] = &sAf[chunk * 512 + 256];  // rows 4..7 of chunk
        bDst[c]  = &sB [chunk * 512];
    }

    // ---- reader invariants ----
    const int rsw = r16 & 7;
    // A: fp32 group offsets (in fp32 elements) per kh half
    const int gA0[2] = { (((0 + q * 2)    ) ^ rsw) * 4, (((8 + q * 2)    ) ^ rsw) * 4 };
    const int gA1[2] = { (((0 + q * 2) + 1) ^ rsw) * 4, (((8 + q * 2) + 1) ^ rsw) * 4 };
    // B: bf16 16B-group offsets (8 groups of 8 bf16)
    const int colK0 = ((q)     ^ rsw) * 8;           // kk = 0..31
    const int colK1 = ((q + 4) ^ rsw) * 8;           // kk = 32..63

    floatx4 acc[4][4];
    #pragma unroll
    for (int mi = 0; mi < 4; ++mi)
        #pragma unroll
        for (int ni = 0; ni < 4; ++ni)
            acc[mi][ni] = (floatx4){0.f, 0.f, 0.f, 0.f};

    #pragma unroll
    for (int t = 0; t < 16; ++t) {                   // k0 = 64*t, fully unrolled
        __syncthreads();   // previous tile's compute done before overwrite
        #pragma unroll
        for (int c = 0; c < 4; ++c) {
            gload16(aSrc0[c] + 64 * t, aDst0[c]);    // +256*t B -> imm offset
            gload16(aSrc1[c] + 64 * t, aDst1[c]);
            gload16(bSrc[c]  + 64 * t, bDst[c]);     // +128*t B -> imm offset
        }
        __syncthreads();   // loads visible (vmcnt(0) drain — proven skeleton)

        #pragma unroll
        for (int kh = 0; kh < 2; ++kh) {
            const int colB = kh ? colK1 : colK0;
            bf16x8 af[4], bfv[4];
            #pragma unroll
            for (int i = 0; i < 4; ++i) {
                const int rowOff = (mBase + 16 * i + r16) * 64;
                float4 lo = *(const float4*)&sAf[rowOff + gA0[kh]];
                float4 hi = *(const float4*)&sAf[rowOff + gA1[kh]];
                union { unsigned u[4]; bf16x8 v; } cvt;
                cvt.u[0] = pk2(lo.x, lo.y); cvt.u[1] = pk2(lo.z, lo.w);
                cvt.u[2] = pk2(hi.x, hi.y); cvt.u[3] = pk2(hi.z, hi.w);
                af[i] = cvt.v;
            }
            #pragma unroll
            for (int i = 0; i < 4; ++i)
                bfv[i] = *(const bf16x8*)&sB[(nBase + 16 * i + r16) * 64 + colB];
            #pragma unroll
            for (int mi = 0; mi < 4; ++mi)
                #pragma unroll
                for (int ni = 0; ni < 4; ++ni)
                    acc[mi][ni] = __builtin_amdgcn_mfma_f32_16x16x32_bf16(
                        af[mi], bfv[ni], acc[mi][ni], 0, 0, 0);
        }
    }

    // epilogue: C[m][n] = acc + mixed_b[b][n]
    float bv[4];
    #pragma unroll
    for (int ni = 0; ni < 4; ++ni)
        bv[ni] = mb[b * DOUT + tileN + nBase + 16 * ni + r16];

    #pragma unroll
    for (int mi = 0; mi < 4; ++mi) {
        #pragma unroll
        for (int rr = 0; rr < 4; ++rr) {
            const int row = tileM + mBase + 16 * mi + q * 4 + rr;
            float* orow = out + (long)b * SS * DOUT + (long)row * DOUT;
            #pragma unroll
            for (int ni = 0; ni < 4; ++ni)
                orow[tileN + nBase + 16 * ni + r16] = acc[mi][ni][rr] + bv[ni];
        }
    }
}

extern "C" void kernel_launch(void* const* d_in, const int* in_sizes, int n_in,
                              void* d_out, int out_size, void* d_ws, size_t ws_size,
                              hipStream_t stream) {
    const float* x    = (const float*)d_in[0];   // [8,2048,1024]
    const float* p    = (const float*)d_in[1];   // [8,16]
    const float* w    = (const float*)d_in[2];   // [16,1024,1024]
    const float* bias = (const float*)d_in[3];   // [16,1024]
    float* out = (float*)d_out;                  // [8,2048,1024]

    // workspace layout: mixed_w bf16 (16 MiB) | mixed_b fp32 (32 KiB)
    unsigned short* mw = (unsigned short*)d_ws;
    float*          mb = (float*)((char*)d_ws + (size_t)16777216);

    prep_kernel<<<dim3(2080), 256, 0, stream>>>(p, w, bias, mw, mb);

    dim3 ggrid(BB, DOUT / 128, SS / 128);        // (8,8,16) = 1024 blocks
    gemm_kernel<<<ggrid, 256, 0, stream>>>(x, mw, mb, out);
}

// Round 9
// 210.451 us; speedup vs baseline: 1.1296x; 1.1296x over previous
//
#include <hip/hip_runtime.h>
#include <hip/hip_bf16.h>
#include <stdint.h>

// Problem constants
#define BB 8
#define SS 2048
#define NEXP 16
#define DIN 1024
#define DOUT 1024

typedef short bf16x8 __attribute__((ext_vector_type(8)));
typedef float floatx4 __attribute__((ext_vector_type(4)));
typedef float f32x4 __attribute__((ext_vector_type(4)));   // native vec for NT builtins

// fp32 -> bf16 round-to-nearest-even (bit trick; inputs are normal floats)
__device__ __forceinline__ unsigned short f2bf(float f) {
    union { float f; unsigned int u; } v; v.f = f;
    unsigned int u = v.u;
    unsigned int r = u + 0x7FFFu + ((u >> 16) & 1u);
    return (unsigned short)(r >> 16);
}

// 2x fp32 -> packed bf16x2 (hardware v_cvt_pk_bf16_f32, RNE — same rounding
// as f2bf for normal floats)
__device__ __forceinline__ unsigned pk2(float a, float b) {
    __hip_bfloat162 h = __float22bfloat162_rn(float2{a, b});
    union { __hip_bfloat162 h; unsigned u; } cv; cv.h = h;
    return cv.u;
}

// async global->LDS, 16B per lane. LDS dest = wave-uniform base + lane*16.
__device__ __forceinline__ void gload16(const void* g, void* l) {
    __builtin_amdgcn_global_load_lds(
        (const __attribute__((address_space(1))) void*)g,
        (__attribute__((address_space(3))) void*)l,
        16, 0, 0);
}

// ---------------------------------------------------------------------------
// R12 = R11 with the nontemporal-load compile error fixed (native
// ext_vector_type float4 instead of HIP_vector_type — the builtin requires
// a native vector element type). No other changes.
// R11 rationale (stands): R5 dispatch data shows xconv work = 42 us
// (2.2 TB/s) while wmix streams 5.3 TB/s in the same pipeline -> xconv's
// 8 B/lane stores + read-once L2 pollution are the suspects, not a HW ceiling.
//   - uint4 stores: 16 B/lane, wave writes 1 KB/instr
//   - v_cvt_pk_bf16_f32 (4 VALU per 8 floats)
//   - nontemporal x loads (read-once; preserve L3 for xb/mw/out)
// ---------------------------------------------------------------------------

// Kernel 1: weight mix + bias mix (proven ~15 us @ 5.3 TB/s)
__global__ __launch_bounds__(256) void prep_kernel(
    const float* __restrict__ p, const float* __restrict__ w,
    const float* __restrict__ bias,
    unsigned short* __restrict__ mw, float* __restrict__ mb)
{
    const int tid = threadIdx.x;
    const int blk = blockIdx.x;

    if (blk < 2048) {                       // ---- weight mix ----
        __shared__ float sp[BB * NEXP];
        if (tid < BB * NEXP) sp[tid] = p[tid];
        __syncthreads();
        const long t  = (long)blk * 256 + tid;      // 0..524287
        const long j2 = t * 2;                      // column pair
        float acc[BB][2];
        #pragma unroll
        for (int b = 0; b < BB; ++b) { acc[b][0] = 0.f; acc[b][1] = 0.f; }
        #pragma unroll
        for (int n = 0; n < NEXP; ++n) {
            float2 wv = *(const float2*)(w + (long)n * DOUT * DIN + j2);
            #pragma unroll
            for (int b = 0; b < BB; ++b) {
                float pb = sp[b * NEXP + n];
                acc[b][0] += pb * wv.x; acc[b][1] += pb * wv.y;
            }
        }
        #pragma unroll
        for (int b = 0; b < BB; ++b) {
            unsigned o = (unsigned)f2bf(acc[b][0]) | ((unsigned)f2bf(acc[b][1]) << 16);
            *(unsigned*)(mw + (long)b * DOUT * DIN + j2) = o;
        }
    } else {                                // ---- bias mix (tiny) ----
        const long t = (long)(blk - 2048) * 256 + tid;    // 0..8191
        const int b = (int)(t >> 10), i = (int)(t & 1023);
        float s = 0.f;
        #pragma unroll
        for (int n = 0; n < NEXP; ++n) s += p[b * NEXP + n] * bias[n * DOUT + i];
        mb[t] = s;
    }
}

// Kernel 2: x fp32 -> bf16 stream, v2.
// 2048 blocks x 256 thr x 4 uint4-outputs. Per output: 2 float4 NT loads
// (the instruction pair jointly covers each cache line fully) -> 4 cvt_pk
// -> 1 uint4 store (wave: 1 KB contiguous).
__global__ __launch_bounds__(256) void xconv_kernel(
    const float* __restrict__ x, unsigned short* __restrict__ xb)
{
    const f32x4* xv = (const f32x4*)x;
    uint4* xo = (uint4*)xb;
    const int base = blockIdx.x * 1024 + threadIdx.x;   // uint4 index
    #pragma unroll
    for (int u = 0; u < 4; ++u) {
        const int o = base + u * 256;
        f32x4 a = __builtin_nontemporal_load(&xv[2 * o]);
        f32x4 b = __builtin_nontemporal_load(&xv[2 * o + 1]);
        uint4 r;
        r.x = pk2(a.x, a.y); r.y = pk2(a.z, a.w);
        r.z = pk2(b.x, b.y); r.w = pk2(b.z, b.w);
        xo[o] = r;
    }
}

// ---------------------------------------------------------------------------
// Kernel 3: batched GEMM — R9 VERBATIM (proven 44.5 us, MfmaUtil 30%,
// 0 bank conflicts, FETCH 34 MB). gload_lds both operands, 2 barriers/iter,
// XOR swizzle, fully unrolled K, grid (B,N,M) id%8==b -> per-XCD L2.
// ---------------------------------------------------------------------------
__global__ __launch_bounds__(256) void gemm_kernel(
    const unsigned short* __restrict__ xb,   // [B][S][DIN] bf16
    const unsigned short* __restrict__ mw,   // [B][DOUT][DIN] bf16
    const float* __restrict__ mb,            // [B][DOUT] fp32
    float* __restrict__ out)                 // [B][S][DOUT] fp32
{
    __shared__ __align__(16) unsigned short sA[128 * 64];  // 16 KB
    __shared__ __align__(16) unsigned short sB[128 * 64];  // 16 KB

    const int tid  = threadIdx.x;
    const int wave = tid >> 6;
    const int lane = tid & 63;
    const int b    = blockIdx.x;          // batch -> XCD (id % 8 == b)
    const int tileN = blockIdx.y * 128;   // over DOUT
    const int tileM = blockIdx.z * 128;   // over S

    const unsigned short* Ag = xb + (long)b * SS * DIN;
    const unsigned short* Bg = mw + (long)b * DOUT * DIN;

    const int q     = lane >> 4;     // quad 0..3
    const int r16   = lane & 15;
    const int mBase = 64 * (wave >> 1);
    const int nBase = 64 * (wave & 1);

    // staging: each wave owns 4 chunks of 1KB (8 rows x 64 bf16) for A and B
    const int sRow   = lane >> 3;                    // 0..7 row within chunk
    const int sColSw = (((lane & 7) ^ sRow) * 8);    // XOR-swizzled source column

    // hoisted global source bases + LDS destinations (loop-invariant)
    const unsigned short* aSrc[4]; const unsigned short* bSrc[4];
    unsigned short* aDst[4]; unsigned short* bDst[4];
    #pragma unroll
    for (int c = 0; c < 4; ++c) {
        const int chunk = wave * 4 + c;              // 0..15
        const int row   = chunk * 8 + sRow;          // 0..127
        aSrc[c] = Ag + (long)(tileM + row) * DIN + sColSw;
        bSrc[c] = Bg + (long)(tileN + row) * DIN + sColSw;
        aDst[c] = &sA[chunk * 512];
        bDst[c] = &sB[chunk * 512];
    }

    // reader: XOR-swizzled 16B-group offsets for the two kk halves (invariant)
    const int swz  = r16 & 7;
    const int colK0 = ((q)     ^ swz) * 8;           // kk = 0..31  (group q)
    const int colK1 = ((q + 4) ^ swz) * 8;           // kk = 32..63 (group q+4)

    floatx4 acc[4][4];
    #pragma unroll
    for (int mi = 0; mi < 4; ++mi)
        #pragma unroll
        for (int ni = 0; ni < 4; ++ni)
            acc[mi][ni] = (floatx4){0.f, 0.f, 0.f, 0.f};

    #pragma unroll
    for (int t = 0; t < 16; ++t) {                   // k0 = 64*t, fully unrolled
        __syncthreads();   // previous tile's compute done before overwrite
        #pragma unroll
        for (int c = 0; c < 4; ++c) {
            gload16(aSrc[c] + 64 * t, aDst[c]);      // +128*t bytes -> imm offset
            gload16(bSrc[c] + 64 * t, bDst[c]);
        }
        __syncthreads();   // loads visible

        #pragma unroll
        for (int kh = 0; kh < 2; ++kh) {
            const int col = kh ? colK1 : colK0;
            bf16x8 af[4], bfv[4];
            #pragma unroll
            for (int i = 0; i < 4; ++i)
                af[i] = *(const bf16x8*)&sA[(mBase + 16 * i + r16) * 64 + col];
            #pragma unroll
            for (int i = 0; i < 4; ++i)
                bfv[i] = *(const bf16x8*)&sB[(nBase + 16 * i + r16) * 64 + col];
            #pragma unroll
            for (int mi = 0; mi < 4; ++mi)
                #pragma unroll
                for (int ni = 0; ni < 4; ++ni)
                    acc[mi][ni] = __builtin_amdgcn_mfma_f32_16x16x32_bf16(
                        af[mi], bfv[ni], acc[mi][ni], 0, 0, 0);
        }
    }

    // epilogue: C[m][n] = acc + mixed_b[b][n]
    float bv[4];
    #pragma unroll
    for (int ni = 0; ni < 4; ++ni)
        bv[ni] = mb[b * DOUT + tileN + nBase + 16 * ni + r16];

    #pragma unroll
    for (int mi = 0; mi < 4; ++mi) {
        #pragma unroll
        for (int rr = 0; rr < 4; ++rr) {
            const int row = tileM + mBase + 16 * mi + q * 4 + rr;
            float* orow = out + (long)b * SS * DOUT + (long)row * DOUT;
            #pragma unroll
            for (int ni = 0; ni < 4; ++ni)
                orow[tileN + nBase + 16 * ni + r16] = acc[mi][ni][rr] + bv[ni];
        }
    }
}

extern "C" void kernel_launch(void* const* d_in, const int* in_sizes, int n_in,
                              void* d_out, int out_size, void* d_ws, size_t ws_size,
                              hipStream_t stream) {
    const float* x    = (const float*)d_in[0];   // [8,2048,1024]
    const float* p    = (const float*)d_in[1];   // [8,16]
    const float* w    = (const float*)d_in[2];   // [16,1024,1024]
    const float* bias = (const float*)d_in[3];   // [16,1024]
    float* out = (float*)d_out;                  // [8,2048,1024]

    // workspace layout: x_bf16 (32 MiB) | mixed_w bf16 (16 MiB) | mixed_b fp32 (32 KiB)
    unsigned short* xb = (unsigned short*)d_ws;
    unsigned short* mw = (unsigned short*)((char*)d_ws + (size_t)33554432);
    float*          mb = (float*)((char*)d_ws + (size_t)33554432 + 16777216);

    prep_kernel<<<dim3(2080), 256, 0, stream>>>(p, w, bias, mw, mb);
    xconv_kernel<<<dim3(2048), 256, 0, stream>>>(x, xb);

    dim3 ggrid(BB, DOUT / 128, SS / 128);        // (8,8,16) = 1024 blocks
    gemm_kernel<<<ggrid, 256, 0, stream>>>(xb, mw, mb, out);
}